// Round 1
// baseline (153.003 us; speedup 1.0000x reference)
//
#include <hip/hip_runtime.h>

// GQA causal SDPA prefill, S=2048, H=32, G=8 kv-heads, D=128, fp32 in/out.
// Round 7: 32-row waves + 32x32x16 MFMA + in-register P (swapped QK^T,
// cvt_pk_bf16 + permlane32_swap). Eliminates the P LDS round-trip and
// halves K/V LDS frag traffic per output (wave reads each K/V tile once
// for 32 rows instead of 16). Block = 256 threads = 4 waves = 4 heads of
// one kv-group x 32 q-rows. LDS 66 KB -> 2 blocks/CU. Same (b, b+256)
// CU-pair balance (nt sums to 33) and one barrier per 64-key tile.

#define SEQ    2048
#define NH     32
#define NKV    8
#define DHEAD  128
#define QROW   (NH * DHEAD)    // 4096
#define KVROW  (NKV * DHEAD)   // 1024
#define SCALE  0.08838834764831845f
#define LOG2E  1.4426950408889634f
#define BN     64              // keys per tile
#define VSTRP  132             // prep transpose LDS stride

typedef __attribute__((ext_vector_type(8))) short bf16x8;
typedef __attribute__((ext_vector_type(8))) unsigned short u16x8;
typedef __attribute__((ext_vector_type(16))) float f32x16;
typedef __attribute__((ext_vector_type(4))) unsigned int u32x4;

static __device__ __forceinline__ unsigned short f2bf(float f) {
  unsigned int u = __float_as_uint(f);
  return (unsigned short)((u + 0x7fffu + ((u >> 16) & 1u)) >> 16);
}

static __device__ __forceinline__ unsigned cvtpk_bf16(float lo, float hi) {
  unsigned r;
  asm("v_cvt_pk_bf16_f32 %0, %1, %2" : "=v"(r) : "v"(lo), "v"(hi));
  return r;
}

static __device__ __forceinline__ f32x16 zero16() {
  f32x16 z;
#pragma unroll
  for (int i = 0; i < 16; ++i) z[i] = 0.f;
  return z;
}

// ---------------- prep: fp32 [t][g][d] -> bf16 Kg [g][t][d], VTg [g][d][t] ----
// 16-row tiles, 1024 blocks (4 blocks/CU) for latency robustness.
__global__ __launch_bounds__(256) void prep_kernel(
    const float* __restrict__ K, const float* __restrict__ V,
    unsigned short* __restrict__ Kg, unsigned short* __restrict__ VTg) {
  __shared__ unsigned short Vs[16 * VSTRP];
  const int t0  = blockIdx.x * 16;
  const int g   = blockIdx.y;
  const int tid = threadIdx.x;
#pragma unroll
  for (int e = 0; e < 2; ++e) {
    int fi = e * 256 + tid;   // 0..511 = 16 rows x 32 float4
    int t  = fi >> 5;
    int c4 = fi & 31;
    const float4 kv = *(const float4*)(K + (size_t)(t0 + t) * KVROW + g * DHEAD + c4 * 4);
    ushort4 kb4 = {f2bf(kv.x), f2bf(kv.y), f2bf(kv.z), f2bf(kv.w)};
    *(ushort4*)(Kg + ((size_t)(g * SEQ + t0 + t) << 7) + c4 * 4) = kb4;
    const float4 vv = *(const float4*)(V + (size_t)(t0 + t) * KVROW + g * DHEAD + c4 * 4);
    ushort4 vb4 = {f2bf(vv.x), f2bf(vv.y), f2bf(vv.z), f2bf(vv.w)};
    *(ushort4*)&Vs[t * VSTRP + c4 * 4] = vb4;
  }
  __syncthreads();
  {
    int d  = tid >> 1;   // 0..127
    int tb = tid & 1;    // 8-key block
    u16x8 o;
#pragma unroll
    for (int j = 0; j < 8; ++j) o[j] = Vs[(tb * 8 + j) * VSTRP + d];
    *(u16x8*)(VTg + (size_t)(g * DHEAD + d) * SEQ + t0 + tb * 8) = o;
  }
}

// LDS layouts (linear dest as global_load_lds requires; XOR pre-swizzled
// on the global source, un-swizzled on the read side):
//   Kb: elem (t,d) at t*128 + (d ^ 8*(t&15))
//   Vb: elem (d,t) at d*64  + (t ^ 8*(d&7))
// 4 waves x 4 chunks x (64 lanes x 8 elems) per 8192-elem buffer.
static __device__ __forceinline__ void stage_kv(
    const unsigned short* __restrict__ Kg, const unsigned short* __restrict__ VTg,
    unsigned short* kbuf, unsigned short* vbuf, int g, int kt, int w, int lane) {
  const int t0 = kt * BN;
#pragma unroll
  for (int c = 0; c < 4; ++c) {
    int off = (w * 4 + c) * 512 + lane * 8;
    int tl  = off >> 7;
    int dsw = (off & 127) ^ (8 * (tl & 15));
    const unsigned short* src = Kg + ((size_t)(g * SEQ + t0 + tl) << 7) + dsw;
    __builtin_amdgcn_global_load_lds(
        (const __attribute__((address_space(1))) void*)src,
        (__attribute__((address_space(3))) void*)(kbuf + (w * 4 + c) * 512), 16, 0, 0);
  }
#pragma unroll
  for (int c = 0; c < 4; ++c) {
    int off = (w * 4 + c) * 512 + lane * 8;
    int dl  = off >> 6;
    int tsw = (off & 63) ^ (8 * (dl & 7));
    const unsigned short* src = VTg + (size_t)(g * DHEAD + dl) * SEQ + t0 + tsw;
    __builtin_amdgcn_global_load_lds(
        (const __attribute__((address_space(1))) void*)src,
        (__attribute__((address_space(3))) void*)(vbuf + (w * 4 + c) * 512), 16, 0, 0);
  }
}

// Per k-step PV: transpose P^T (in regs) -> A-frag via cvt_pk + permlane32_swap
// (verified m214v22 pairing: Y0=regs{8s+0,8s+1}, Y1=regs{8s+4,8s+5} -> word0/word2),
// then 4 MFMAs against V^T frags from LDS.
#define PV_KSTEP(PP, S, KS2)                                                     \
  do {                                                                           \
    unsigned y0 = cvtpk_bf16((PP)[(2 * (S)) * 4 + 0], (PP)[(2 * (S)) * 4 + 1]);  \
    unsigned z0 = cvtpk_bf16((PP)[(2 * (S)) * 4 + 2], (PP)[(2 * (S)) * 4 + 3]);  \
    unsigned y1 = cvtpk_bf16((PP)[(2 * (S) + 1) * 4 + 0], (PP)[(2 * (S) + 1) * 4 + 1]); \
    unsigned z1 = cvtpk_bf16((PP)[(2 * (S) + 1) * 4 + 2], (PP)[(2 * (S) + 1) * 4 + 3]); \
    asm("v_permlane32_swap_b32 %0, %1" : "+v"(y0), "+v"(y1));                    \
    asm("v_permlane32_swap_b32 %0, %1" : "+v"(z0), "+v"(z1));                    \
    u32x4 paw = (u32x4){y0, z0, y1, z1};                                         \
    bf16x8 pa = __builtin_bit_cast(bf16x8, paw);                                 \
    const int tcol = (KS2) * 16 + hi * 8;                                        \
    _Pragma("unroll")                                                            \
    for (int nd = 0; nd < 4; ++nd) {                                             \
      int drow = nd * 32 + l32;                                                  \
      bf16x8 vf = *(const bf16x8*)&Vb[cur][drow * BN + (tcol ^ (8 * (drow & 7)))]; \
      oacc[nd] = __builtin_amdgcn_mfma_f32_32x32x16_bf16(pa, vf, oacc[nd], 0, 0, 0); \
    }                                                                            \
  } while (0)

__global__ __launch_bounds__(256, 2) void sdpa_w32_kernel(
    const float* __restrict__ Q, float* __restrict__ O,
    const unsigned short* __restrict__ Kg, const unsigned short* __restrict__ VTg) {
  __shared__ unsigned short Kb[2][BN * DHEAD];   // 32 KB
  __shared__ unsigned short Vb[2][DHEAD * BN];   // 32 KB
  __shared__ float Ls[4][32];                    // per-wave 1/l broadcast

  // CU-pair balance: b and b+256 share a CU under round-robin dispatch;
  // nt(b) + nt(b+256) == 33. g = b&7 pins bf16 KV (1 MB) to one XCD's L2.
  const int b   = blockIdx.x;
  const int g   = b & 7;
  const int q5  = (b >> 3) & 31;
  const int jj  = (b >= 256) ? q5 : 63 - q5;     // q32-block, 0..63 (heavy first)
  const int q0  = jj * 32;
  const int nt  = (jj >> 1) + 1;                 // 64-key tiles, 1..32
  const int tid = threadIdx.x;
  const int w   = tid >> 6;                      // 0..3
  const int lane = tid & 63;
  const int l32 = lane & 31;
  const int hi  = lane >> 5;
  const int h   = g * 4 + w;                     // wave's q-head

  // ---- Q fragments (B operand: n = l32 = qrow, k = ks*16 + hi*8 + j) ----
  bf16x8 qf[8];
  {
    const float* qp = Q + (size_t)(q0 + l32) * QROW + h * DHEAD + hi * 8;
#pragma unroll
    for (int ks = 0; ks < 8; ++ks) {
      const float4 a = *(const float4*)(qp + ks * 16);
      const float4 c = *(const float4*)(qp + ks * 16 + 4);
      bf16x8 v;
      v[0] = (short)f2bf(a.x * (SCALE * LOG2E));
      v[1] = (short)f2bf(a.y * (SCALE * LOG2E));
      v[2] = (short)f2bf(a.z * (SCALE * LOG2E));
      v[3] = (short)f2bf(a.w * (SCALE * LOG2E));
      v[4] = (short)f2bf(c.x * (SCALE * LOG2E));
      v[5] = (short)f2bf(c.y * (SCALE * LOG2E));
      v[6] = (short)f2bf(c.z * (SCALE * LOG2E));
      v[7] = (short)f2bf(c.w * (SCALE * LOG2E));
      qf[ks] = v;
    }
  }

  f32x16 oacc[4];
#pragma unroll
  for (int i = 0; i < 4; ++i) oacc[i] = zero16();
  float lsum = 0.f;

  stage_kv(Kg, VTg, Kb[0], Vb[0], g, 0, w, lane);
  __syncthreads();

  for (int kt = 0; kt < nt; ++kt) {
    const int cur = kt & 1;
    if (kt + 1 < nt)  // async prefetch; drained by the end-of-loop barrier
      stage_kv(Kg, VTg, Kb[cur ^ 1], Vb[cur ^ 1], g, kt + 1, w, lane);

    const bool diag = (kt == nt - 1);
    const int KB = (diag && !(jj & 1)) ? 1 : 2;  // even-jj diag: upper 32 keys fully masked

    // ---- swapped QK^T: T[key][qrow], A = K (m=key), B = Q (n=qrow) ----
    f32x16 s0 = zero16();
    f32x16 s1 = zero16();
#pragma unroll
    for (int ks = 0; ks < 8; ++ks) {
      const int t = l32;  // kb = 0
      bf16x8 kf = *(const bf16x8*)&Kb[cur][t * DHEAD + (((ks * 16 + hi * 8)) ^ (8 * (t & 15)))];
      s0 = __builtin_amdgcn_mfma_f32_32x32x16_bf16(kf, qf[ks], s0, 0, 0, 0);
    }
    if (KB == 2) {
#pragma unroll
      for (int ks = 0; ks < 8; ++ks) {
        const int t = 32 + l32;  // kb = 1
        bf16x8 kf = *(const bf16x8*)&Kb[cur][t * DHEAD + (((ks * 16 + hi * 8)) ^ (8 * (t & 15)))];
        s1 = __builtin_amdgcn_mfma_f32_32x32x16_bf16(kf, qf[ks], s1, 0, 0, 0);
      }
    }

    // ---- mask + exp2 (lane holds qrow = l32, keys = crow(r,hi)+kb*32) ----
    const int keyb = kt * BN;
    f32x16 p0, p1;
#pragma unroll
    for (int r = 0; r < 16; ++r) {
      const int ko = (r & 3) + 8 * (r >> 2) + 4 * hi;
      float x = s0[r];
      x = (diag && (keyb + ko > q0 + l32)) ? -1e30f : x;
      float e = __builtin_amdgcn_exp2f(x);
      p0[r] = e;
      lsum += e;
    }
    if (KB == 2) {
#pragma unroll
      for (int r = 0; r < 16; ++r) {
        const int ko = 32 + (r & 3) + 8 * (r >> 2) + 4 * hi;
        float x = s1[r];
        x = (diag && (keyb + ko > q0 + l32)) ? -1e30f : x;
        float e = __builtin_amdgcn_exp2f(x);
        p1[r] = e;
        lsum += e;
      }
    }

    // ---- O += P V  (P transposed in-register per 16-key step) ----
    PV_KSTEP(p0, 0, 0);
    PV_KSTEP(p0, 1, 1);
    if (KB == 2) {
      PV_KSTEP(p1, 0, 2);
      PV_KSTEP(p1, 1, 3);
    }

    __syncthreads();   // drains prefetch (vmcnt) + fences buffer reuse
  }

  // ---- epilogue: l = own half + partner half; broadcast 1/l by row via LDS ----
  {
    float tot = lsum + __shfl_xor(lsum, 32);
    if (hi == 0) Ls[w][l32] = 1.f / tot;
  }
  __syncthreads();
#pragma unroll
  for (int nd = 0; nd < 4; ++nd) {
#pragma unroll
    for (int r = 0; r < 16; ++r) {
      const int row = (r & 3) + 8 * (r >> 2) + 4 * hi;
      O[(size_t)(q0 + row) * QROW + h * DHEAD + nd * 32 + l32] = oacc[nd][r] * Ls[w][row];
    }
  }
}

extern "C" void kernel_launch(void* const* d_in, const int* in_sizes, int n_in,
                              void* d_out, int out_size, void* d_ws, size_t ws_size,
                              hipStream_t stream) {
  (void)in_sizes; (void)n_in; (void)out_size; (void)ws_size;
  const float* Q = (const float*)d_in[0];
  const float* K = (const float*)d_in[1];
  const float* V = (const float*)d_in[2];
  float* O = (float*)d_out;
  unsigned short* Kg  = (unsigned short*)d_ws;                 // 4 MB
  unsigned short* VTg = Kg + (size_t)NKV * SEQ * DHEAD;        // 4 MB
  prep_kernel<<<dim3(SEQ / 16, NKV), 256, 0, stream>>>(K, V, Kg, VTg);
  sdpa_w32_kernel<<<512, 256, 0, stream>>>(Q, O, Kg, VTg);
}